// Round 5
// baseline (182.653 us; speedup 1.0000x reference)
//
#include <hip/hip_runtime.h>
#include <math.h>

// Problem: B=16384, D=512, R=64, E=8.
// out = x0 * (sum_e g_e * (x @ V[e]^T C[e] U[e]^T)) + g@b + x*sum(g)
// Folded: VCc[n=e*64+s][d] = sum_r V[e,r,d] C[e,r,s]  (Bt for GEMM1, K=d contig)
//         Ut [d][n=e*64+s] = U[e,d,s]                  (Bt for GEMM2, K=n contig)
//
// R7: counted-vmcnt deep pipeline (T3/T4). R6's __syncthreads-per-step drained
// vmcnt(0) every 300cy of compute -> ~6k cy/step exposed L2 latency (7% Mfma).
// Now: B streamed as ring-4 of 16KB quanta [256n][32K], prefetch depth 3,
// s_waitcnt vmcnt(6) + raw s_barrier (never drain in loop), lgkmcnt(0) before
// closing barrier, setprio around MFMA (T5). 64 steps, 2 phases.
// Epilogue: acc -> LDS transpose (slab is dead) -> coalesced float4 x0/x/out.
// Geometry (R6-verified): 64-row slab, 512thr 8 waves 2m x 4n, wave-tile 32x64,
// acc[2][8]; A/T slab XOR-swizzled; accumulation order bit-identical to R6.

typedef __bf16 bf16_t;
typedef __attribute__((ext_vector_type(8))) __bf16 bf16x8;
typedef __attribute__((ext_vector_type(4))) float  floatx4;

#define MFMA16 __builtin_amdgcn_mfma_f32_16x16x32_bf16

// async 16B/lane global->LDS (LDS dest = wave-uniform base + lane*16)
__device__ __forceinline__ void async16(void* lds, const void* gp) {
  __builtin_amdgcn_global_load_lds(
      (__attribute__((address_space(1))) void*)(gp),
      (__attribute__((address_space(3))) void*)(lds), 16, 0, 0);
}

// ---------------- K0: weight prep, LDS-tiled (verified R5/R6) ---------------
__global__ __launch_bounds__(256) void prep_kernel(
    const float* __restrict__ U, const float* __restrict__ V, const float* __restrict__ C,
    bf16_t* __restrict__ VCc, bf16_t* __restrict__ Ut) {
  const int b = blockIdx.x, t = threadIdx.x;
  if (b < 64) {
    __shared__ alignas(16) char ldsbuf[32768];
    float* ldsC = (float*)ldsbuf;            // [64 r][64 s]
    float* ldsV = (float*)(ldsbuf + 16384);  // [64 r][64 d]
    const int e = b >> 3, db = b & 7;
#pragma unroll
    for (int i = 0; i < 4; ++i) {
      int c = i * 256 + t;
      async16(ldsbuf + c * 16, (const char*)C + (size_t)e * 16384 + c * 16);
    }
#pragma unroll
    for (int i = 0; i < 4; ++i) {
      int c = i * 256 + t, r = c >> 4, cc = c & 15;
      async16(ldsbuf + 16384 + c * 16,
              (const char*)V + (size_t)(e * 64 + r) * 2048 + db * 256 + cc * 16);
    }
    __syncthreads();
    const int s = t & 63, dg = t >> 6;
    float acc16[16];
#pragma unroll
    for (int k = 0; k < 16; ++k) acc16[k] = 0.f;
#pragma unroll 4
    for (int r = 0; r < 64; ++r) {
      float cv = ldsC[r * 64 + s];
      floatx4 v[4];
#pragma unroll
      for (int j = 0; j < 4; ++j) v[j] = *(const floatx4*)(ldsV + r * 64 + dg * 16 + j * 4);
#pragma unroll
      for (int j = 0; j < 4; ++j)
#pragma unroll
        for (int k = 0; k < 4; ++k) acc16[j * 4 + k] = fmaf(v[j][k], cv, acc16[j * 4 + k]);
    }
    bf16_t* dst = VCc + (size_t)(e * 64 + s) * 512 + db * 64 + dg * 16;
    bf16x8 o0, o1;
#pragma unroll
    for (int k = 0; k < 8; ++k) { o0[k] = (bf16_t)acc16[k]; o1[k] = (bf16_t)acc16[8 + k]; }
    *(bf16x8*)dst = o0;
    *(bf16x8*)(dst + 8) = o1;
  } else {
    const int base = (b - 64) * 4096 + t * 16;
    const int d = base >> 9, n0 = base & 511;
    const int e = n0 >> 6, s0 = n0 & 63;
    const float* src = U + ((size_t)e * 512 + d) * 64 + s0;
    bf16x8 o0, o1;
#pragma unroll
    for (int k = 0; k < 8; ++k) { o0[k] = (bf16_t)src[k]; o1[k] = (bf16_t)src[8 + k]; }
    *(bf16x8*)(Ut + base) = o0;
    *(bf16x8*)(Ut + base + 8) = o1;
  }
}

// ---- stage quantum v: Bt rows [h*256,+256), K-bytes [kc*64,+64) -> 16KB ----
// Ring slot v&3. LDS [256 rows][64B]; phys 16B slot of row r = log ^ ((r&7)>>1)
// so a frag read (rows r..r+15, fixed lhi) hits all 8 bank-quads twice (free).
__device__ __forceinline__ void stage_q(char* ring, const char* __restrict__ Bt,
                                        int v, int wave, int t) {
  char* dst = ring + (v & 3) * 16384;
  const char* src = Bt + (size_t)((v >> 4) & 1) * 262144 + (v & 15) * 64;
#pragma unroll
  for (int i = 0; i < 2; ++i) {
    int c = i * 512 + t;                     // 1024 chunks of 16B
    int r = c >> 2, sp = c & 3, sl = sp ^ ((r & 7) >> 1);
    async16(dst + (i * 512 + wave * 64) * 16, src + (size_t)r * 1024 + sl * 16);
  }
}

// ---------------- K1: gate + GEMM1 -> T(LDS) -> GEMM2 -> epilogue ----------
__global__ __launch_bounds__(512, 2) void fused_kernel(
    const float* __restrict__ x0, const float* __restrict__ x,
    const bf16_t* __restrict__ VCc, const bf16_t* __restrict__ Ut,
    const float* __restrict__ Wg, const float* __restrict__ bg,
    const float* __restrict__ bvec, float* __restrict__ out) {
  __shared__ alignas(16) char lds[133120];
  char*  ldsX = lds;                     // [64][1024B] bf16 swizzled: x, then T
  char*  ring = lds + 65536;             // 4 x 16KB B quanta [256 rows][64B]
  float* ldsG = (float*)(lds + 131072);  // [64][8] gates
  const int t = threadIdx.x;
  const int wave = t >> 6, lane = t & 63;
  const int wr = wave >> 2, wc = wave & 3;   // 2m x 4n waves, wave-tile 32x64
  const int lhi = lane >> 4, llo = lane & 15;
  const int m0 = blockIdx.x * 64;

  // ---- stage x slab -> bf16 ldsX (swizzled): 8 chunks of 8 f32 per thread ----
  {
    const float4* xs = (const float4*)(x + (size_t)m0 * 512);
#pragma unroll
    for (int i = 0; i < 8; ++i) {
      int c = i * 512 + t, r = c >> 6, q = c & 63;
      float4 f0 = xs[r * 128 + q * 2];
      float4 f1 = xs[r * 128 + q * 2 + 1];
      bf16x8 v;
      v[0] = (bf16_t)f0.x; v[1] = (bf16_t)f0.y; v[2] = (bf16_t)f0.z; v[3] = (bf16_t)f0.w;
      v[4] = (bf16_t)f1.x; v[5] = (bf16_t)f1.y; v[6] = (bf16_t)f1.z; v[7] = (bf16_t)f1.w;
      int slot = (q & 7) ^ (r & 7);
      *(bf16x8*)(ldsX + r * 1024 + (q >> 3) * 128 + slot * 16) = v;
    }
  }
  // ---- prologue: stage quanta 0,1,2 (drained at the syncthreads below) ----
  stage_q(ring, (const char*)VCc, 0, wave, t);
  stage_q(ring, (const char*)VCc, 1, wave, t);
  stage_q(ring, (const char*)VCc, 2, wave, t);

  // ---- gate: wave handles rows wave*8+p; f32 dot + butterfly + softmax ----
#pragma unroll 1
  for (int p = 0; p < 8; ++p) {
    const int rl = wave * 8 + p;
    const float4* xr = (const float4*)(x + (size_t)(m0 + rl) * 512 + lane * 8);
    float4 xa = xr[0], xb = xr[1];
    float z[8];
#pragma unroll
    for (int e = 0; e < 8; ++e) {
      const float4* wp = (const float4*)(Wg + (size_t)e * 512 + lane * 8);
      float4 wa = wp[0], wb = wp[1];
      z[e] = xa.x * wa.x + xa.y * wa.y + xa.z * wa.z + xa.w * wa.w +
             xb.x * wb.x + xb.y * wb.y + xb.z * wb.z + xb.w * wb.w;
    }
#pragma unroll
    for (int e = 0; e < 8; ++e)
#pragma unroll
      for (int off = 32; off > 0; off >>= 1) z[e] += __shfl_xor(z[e], off, 64);
    if (lane == 0) {
      float mx = -1e30f, ssum = 0.f;
#pragma unroll
      for (int e = 0; e < 8; ++e) { z[e] += bg[e]; mx = fmaxf(mx, z[e]); }
#pragma unroll
      for (int e = 0; e < 8; ++e) { z[e] = __expf(z[e] - mx); ssum += z[e]; }
      float inv = 1.f / ssum;
      float4 ga = {z[0] * inv, z[1] * inv, z[2] * inv, z[3] * inv};
      float4 gb = {z[4] * inv, z[5] * inv, z[6] * inv, z[7] * inv};
      *(float4*)(ldsG + rl * 8) = ga;
      *(float4*)(ldsG + rl * 8 + 4) = gb;
    }
  }
  __syncthreads();   // slab+gates visible; quanta 0-2 complete; vmcnt=0

  // ---- main pipeline: 64 steps (u: phase<<5 | half<<4 | kchunk) ----
  const int rA0 = wr * 32 + llo, rm = llo & 7;
  const char* ap0 = ldsX + rA0 * 1024;
  const char* ap1 = ldsX + (rA0 + 16) * 1024;
  const int bsw = (lhi ^ ((llo & 7) >> 1)) << 4;   // B phys-slot byte offset
  const int rBb = wc * 64 + llo;                   // B base row in quantum
  floatx4 acc[2][8];
#pragma unroll
  for (int i = 0; i < 2; ++i)
#pragma unroll
    for (int jj = 0; jj < 8; ++jj) acc[i][jj] = (floatx4){0.f, 0.f, 0.f, 0.f};

#pragma unroll 1
  for (int u = 0; u < 64; ++u) {
    // stage u+3 (slot (u+3)&3 == (u-1)&3: its readers done at u-1's barrier)
    if (u < 61) {
      const int v = u + 3;
      stage_q(ring, (v >> 5) ? (const char*)Ut : (const char*)VCc, v, wave, t);
      asm volatile("s_waitcnt vmcnt(6)" ::: "memory");   // quantum u complete
    } else if (u == 61) {
      asm volatile("s_waitcnt vmcnt(4)" ::: "memory");
    } else if (u == 62) {
      asm volatile("s_waitcnt vmcnt(2)" ::: "memory");
    } else {
      asm volatile("s_waitcnt vmcnt(0)" ::: "memory");
    }
    asm volatile("s_barrier" ::: "memory");              // all waves: slot full

    const int kk = u & 15;
    const int g0 = (kk >> 1) * 128, sq = 4 * (kk & 1);
    bf16x8 a0 = *(const bf16x8*)(ap0 + g0 + (((sq + lhi) ^ rm) << 4));
    bf16x8 a1 = *(const bf16x8*)(ap1 + g0 + (((sq + lhi) ^ rm) << 4));
    const char* bq = ring + (u & 3) * 16384;
    bf16x8 bfr[4];
#pragma unroll
    for (int j = 0; j < 4; ++j)
      bfr[j] = *(const bf16x8*)(bq + (rBb + j * 16) * 64 + bsw);

    __builtin_amdgcn_s_setprio(1);
    if (u < 32) {                                        // half = (u>>4)&1
      if ((u & 16) == 0) {
#pragma unroll
        for (int j = 0; j < 4; ++j) {
          acc[0][j] = MFMA16(a0, bfr[j], acc[0][j], 0, 0, 0);
          acc[1][j] = MFMA16(a1, bfr[j], acc[1][j], 0, 0, 0);
        }
      } else {
#pragma unroll
        for (int j = 0; j < 4; ++j) {
          acc[0][4 + j] = MFMA16(a0, bfr[j], acc[0][4 + j], 0, 0, 0);
          acc[1][4 + j] = MFMA16(a1, bfr[j], acc[1][4 + j], 0, 0, 0);
        }
      }
    } else {
      if ((u & 16) == 0) {
#pragma unroll
        for (int j = 0; j < 4; ++j) {
          acc[0][j] = MFMA16(a0, bfr[j], acc[0][j], 0, 0, 0);
          acc[1][j] = MFMA16(a1, bfr[j], acc[1][j], 0, 0, 0);
        }
      } else {
#pragma unroll
        for (int j = 0; j < 4; ++j) {
          acc[0][4 + j] = MFMA16(a0, bfr[j], acc[0][4 + j], 0, 0, 0);
          acc[1][4 + j] = MFMA16(a1, bfr[j], acc[1][4 + j], 0, 0, 0);
        }
      }
    }
    __builtin_amdgcn_s_setprio(0);
    asm volatile("s_waitcnt lgkmcnt(0)" ::: "memory");   // frags read before restage
    asm volatile("s_barrier" ::: "memory");              // slot free

    if (u == 31) {
      // ---- junction: T = gate-scaled xvc overwrites ldsX (same swizzle) ----
#pragma unroll
      for (int p = 0; p < 2; ++p) {
#pragma unroll
        for (int i = 0; i < 2; ++i)
#pragma unroll
          for (int r = 0; r < 4; ++r) {
            int ml = wr * 32 + i * 16 + lhi * 4 + r;     // C/D: col=lane&15, row=quad*4+reg
            float gv = ldsG[ml * 8 + p * 4 + wc];        // e = p*4+wc (wave-uniform)
#pragma unroll
            for (int j = 0; j < 4; ++j) {
              int n = p * 256 + wc * 64 + j * 16 + llo;
              int qc = n >> 3, slot = (qc & 7) ^ (ml & 7);
              *(bf16_t*)(ldsX + ml * 1024 + (qc >> 3) * 128 + slot * 16 + (n & 7) * 2) =
                  (bf16_t)(acc[i][p * 4 + j][r] * gv);
            }
          }
      }
      asm volatile("s_waitcnt lgkmcnt(0)" ::: "memory"); // T writes retired
      asm volatile("s_barrier" ::: "memory");            // T visible to all
#pragma unroll
      for (int i = 0; i < 2; ++i)
#pragma unroll
        for (int jj = 0; jj < 8; ++jj) acc[i][jj] = (floatx4){0.f, 0.f, 0.f, 0.f};
    }
  }

  // ---- epilogue: acc -> LDS transpose (slab dead) -> coalesced f4 stores ----
  float* ldsF = (float*)ldsX;                            // [64][256] f32 per half
#pragma unroll 1
  for (int p = 0; p < 2; ++p) {
    if (p == 0) {
#pragma unroll
      for (int i = 0; i < 2; ++i)
#pragma unroll
        for (int j = 0; j < 4; ++j)
#pragma unroll
          for (int r = 0; r < 4; ++r) {
            int ml = wr * 32 + i * 16 + lhi * 4 + r;
            ldsF[ml * 256 + wc * 64 + j * 16 + llo] = acc[i][j][r];
          }
    } else {
#pragma unroll
      for (int i = 0; i < 2; ++i)
#pragma unroll
        for (int j = 0; j < 4; ++j)
#pragma unroll
          for (int r = 0; r < 4; ++r) {
            int ml = wr * 32 + i * 16 + lhi * 4 + r;
            ldsF[ml * 256 + wc * 64 + j * 16 + llo] = acc[i][4 + j][r];
          }
    }
    __syncthreads();
    floatx4 bb4[8];
#pragma unroll
    for (int e = 0; e < 8; ++e)
      bb4[e] = *(const floatx4*)(bvec + (size_t)e * 512 + p * 256 + lane * 4);
#pragma unroll
    for (int k = 0; k < 8; ++k) {
      int row = k * 8 + wave;                            // wave-uniform
      floatx4 v = *(const floatx4*)(ldsF + row * 256 + lane * 4);
      floatx4 ga = *(const floatx4*)(ldsG + row * 8);
      floatx4 gb = *(const floatx4*)(ldsG + row * 8 + 4);
      float g8[8] = {ga[0], ga[1], ga[2], ga[3], gb[0], gb[1], gb[2], gb[3]};
      float gsum = ga[0] + ga[1] + ga[2] + ga[3] + gb[0] + gb[1] + gb[2] + gb[3];
      size_t idx = (size_t)(m0 + row) * 512 + p * 256 + lane * 4;
      floatx4 xv0 = *(const floatx4*)(x0 + idx);
      floatx4 xv  = *(const floatx4*)(x + idx);
      floatx4 o;
#pragma unroll
      for (int c = 0; c < 4; ++c) {
        float bias = 0.f;
#pragma unroll
        for (int e = 0; e < 8; ++e) bias = fmaf(g8[e], bb4[e][c], bias);
        o[c] = xv0[c] * v[c] + bias + xv[c] * gsum;
      }
      *(floatx4*)(out + idx) = o;
    }
    if (p == 0) __syncthreads();                         // before half-1 overwrite
  }
}

// ---------------- launch ----------------------------------------------------
extern "C" void kernel_launch(void* const* d_in, const int* in_sizes, int n_in,
                              void* d_out, int out_size, void* d_ws, size_t ws_size,
                              hipStream_t stream) {
  const float* x0 = (const float*)d_in[0];
  const float* x  = (const float*)d_in[1];
  const float* U  = (const float*)d_in[2];
  const float* V  = (const float*)d_in[3];
  const float* C  = (const float*)d_in[4];
  const float* bv = (const float*)d_in[5];
  const float* Wg = (const float*)d_in[6];
  const float* bg = (const float*)d_in[7];
  float* out = (float*)d_out;

  char* ws = (char*)d_ws;
  bf16_t* VCc = (bf16_t*)(ws);              // 524,288 B
  bf16_t* Ut  = (bf16_t*)(ws + 524288);     // 524,288 B

  prep_kernel<<<128, 256, 0, stream>>>(U, V, C, VCc, Ut);
  fused_kernel<<<256, 512, 0, stream>>>(x0, x, VCc, Ut, Wg, bg, bv, out);
}

// Round 6
// 165.516 us; speedup vs baseline: 1.1035x; 1.1035x over previous
//
#include <hip/hip_runtime.h>
#include <math.h>

// Problem: B=16384, D=512, R=64, E=8.
// out = x0 * (sum_e g_e * (x @ V[e]^T C[e] U[e]^T)) + g@b + x*sum(g)
// Folded: VCc[n=e*64+s][d] = sum_r V[e,r,d] C[e,r,s]  (Bt for GEMM1, K=d contig)
//         Ut [d][n=e*64+s] = U[e,d,s]                  (Bt for GEMM2, K=n contig)
//
// R8: UN-FUSE. R3-R7 proved the 1-block/CU fused structure is the ceiling
// (84-110us at 7% Mfma regardless of pipeline style: no co-resident block to
// absorb barrier/junction stalls). Back to 4 kernels a la the 163us session
// best, upgraded: prep = R5 LDS-tiled (~3us); gate verbatim; GEMMs widened to
// 128x128 tiles (m97 geometry: 4 waves, wave-tile 64x64, acc[4][4], 32KB LDS
// single-buffered, 2 barriers/step, 8 K-steps) at 3 blocks/CU -> inter-block
// overlap hides the per-step drains. T takes a 32MB HBM round-trip (~5us, the
// price of 3 blocks/CU). Accumulation order identical to verified kernels.

typedef __bf16 bf16_t;
typedef __attribute__((ext_vector_type(8))) __bf16 bf16x8;
typedef __attribute__((ext_vector_type(4))) __bf16 bf16x4;
typedef __attribute__((ext_vector_type(4))) float  floatx4;

#define MFMA16 __builtin_amdgcn_mfma_f32_16x16x32_bf16

// async 16B/lane global->LDS (LDS dest = wave-uniform base + lane*16)
__device__ __forceinline__ void async16(void* lds, const void* gp) {
  __builtin_amdgcn_global_load_lds(
      (__attribute__((address_space(1))) void*)(gp),
      (__attribute__((address_space(3))) void*)(lds), 16, 0, 0);
}

// ---------------- K0: weight prep, LDS-tiled (verified R5/R6/R7) ------------
__global__ __launch_bounds__(256) void prep_kernel(
    const float* __restrict__ U, const float* __restrict__ V, const float* __restrict__ C,
    bf16_t* __restrict__ VCc, bf16_t* __restrict__ Ut) {
  const int b = blockIdx.x, t = threadIdx.x;
  if (b < 64) {
    __shared__ alignas(16) char ldsbuf[32768];
    float* ldsC = (float*)ldsbuf;            // [64 r][64 s]
    float* ldsV = (float*)(ldsbuf + 16384);  // [64 r][64 d]
    const int e = b >> 3, db = b & 7;
#pragma unroll
    for (int i = 0; i < 4; ++i) {
      int c = i * 256 + t;
      async16(ldsbuf + c * 16, (const char*)C + (size_t)e * 16384 + c * 16);
    }
#pragma unroll
    for (int i = 0; i < 4; ++i) {
      int c = i * 256 + t, r = c >> 4, cc = c & 15;
      async16(ldsbuf + 16384 + c * 16,
              (const char*)V + (size_t)(e * 64 + r) * 2048 + db * 256 + cc * 16);
    }
    __syncthreads();
    const int s = t & 63, dg = t >> 6;
    float acc16[16];
#pragma unroll
    for (int k = 0; k < 16; ++k) acc16[k] = 0.f;
#pragma unroll 4
    for (int r = 0; r < 64; ++r) {
      float cv = ldsC[r * 64 + s];
      floatx4 v[4];
#pragma unroll
      for (int j = 0; j < 4; ++j) v[j] = *(const floatx4*)(ldsV + r * 64 + dg * 16 + j * 4);
#pragma unroll
      for (int j = 0; j < 4; ++j)
#pragma unroll
        for (int k = 0; k < 4; ++k) acc16[j * 4 + k] = fmaf(v[j][k], cv, acc16[j * 4 + k]);
    }
    bf16_t* dst = VCc + (size_t)(e * 64 + s) * 512 + db * 64 + dg * 16;
    bf16x8 o0, o1;
#pragma unroll
    for (int k = 0; k < 8; ++k) { o0[k] = (bf16_t)acc16[k]; o1[k] = (bf16_t)acc16[8 + k]; }
    *(bf16x8*)dst = o0;
    *(bf16x8*)(dst + 8) = o1;
  } else {
    const int base = (b - 64) * 4096 + t * 16;
    const int d = base >> 9, n0 = base & 511;
    const int e = n0 >> 6, s0 = n0 & 63;
    const float* src = U + ((size_t)e * 512 + d) * 64 + s0;
    bf16x8 o0, o1;
#pragma unroll
    for (int k = 0; k < 8; ++k) { o0[k] = (bf16_t)src[k]; o1[k] = (bf16_t)src[8 + k]; }
    *(bf16x8*)(Ut + base) = o0;
    *(bf16x8*)(Ut + base + 8) = o1;
  }
}

// ---------------- K1: x -> bf16 cast + gate softmax (session-verified) -----
__global__ __launch_bounds__(256) void gate_kernel(
    const float* __restrict__ x, const float* __restrict__ Wg, const float* __restrict__ bg,
    bf16_t* __restrict__ xbf, float* __restrict__ g) {
  int wave = threadIdx.x >> 6, lane = threadIdx.x & 63;
  int row = blockIdx.x * 4 + wave;
  const float4* xr = (const float4*)(x + (size_t)row * 512);
  float4 v0 = xr[lane];
  float4 v1 = xr[lane + 64];
  bf16x4* xb = (bf16x4*)(xbf + (size_t)row * 512);
  bf16x4 b0, b1;
  b0.x = (bf16_t)v0.x; b0.y = (bf16_t)v0.y; b0.z = (bf16_t)v0.z; b0.w = (bf16_t)v0.w;
  b1.x = (bf16_t)v1.x; b1.y = (bf16_t)v1.y; b1.z = (bf16_t)v1.z; b1.w = (bf16_t)v1.w;
  xb[lane] = b0;
  xb[lane + 64] = b1;
  float acc[8];
#pragma unroll
  for (int e = 0; e < 8; ++e) {
    const float4* wp = (const float4*)(Wg + (size_t)e * 512);
    float4 w0 = wp[lane], w1 = wp[lane + 64];
    acc[e] = v0.x * w0.x + v0.y * w0.y + v0.z * w0.z + v0.w * w0.w +
             v1.x * w1.x + v1.y * w1.y + v1.z * w1.z + v1.w * w1.w;
  }
#pragma unroll
  for (int e = 0; e < 8; ++e) {
#pragma unroll
    for (int off = 32; off > 0; off >>= 1) acc[e] += __shfl_xor(acc[e], off, 64);
  }
  float z[8], mx = -1e30f;
#pragma unroll
  for (int e = 0; e < 8; ++e) { z[e] = acc[e] + bg[e]; mx = fmaxf(mx, z[e]); }
  float s = 0.f;
#pragma unroll
  for (int e = 0; e < 8; ++e) { z[e] = __expf(z[e] - mx); s += z[e]; }
  float inv = 1.f / s;
  if (lane == 0) {
#pragma unroll
    for (int e = 0; e < 8; ++e) g[(size_t)row * 8 + e] = z[e] * inv;
  }
}

// ---------------- shared GEMM core: 128x128 tile, BK=64, 4 waves 64x64 -----
// A [M][512] bf16 row-major; Bt [N][512] bf16 (column n's K contiguous).
// LDS chunk swizzle: 16B slot q of row r holds global slot q^(r&7) within the
// 128B row (inverse-swizzled source, linear global_load_lds dest; read XORs
// back). Single-buffered, 2 barriers/K-step; 3 blocks/CU absorb the drains.
__device__ __forceinline__ void gemm_core128(
    const bf16_t* __restrict__ A, const bf16_t* __restrict__ Bt,
    int m0, int n0, int t, floatx4 acc[4][4]) {
  __shared__ alignas(16) char lds[32768];
  char* ldsA = lds;           // [128 rows][128B]
  char* ldsB = lds + 16384;   // [128 rows][128B]
  const int wave = t >> 6, lane = t & 63;
  const int wr = wave >> 1, wc = wave & 1;
  const int lhi = lane >> 4, llo = lane & 15;
#pragma unroll 1
  for (int kt = 0; kt < 8; ++kt) {
    __syncthreads();  // protect LDS from previous iter's readers
#pragma unroll
    for (int i = 0; i < 4; ++i) {          // A: 1024 slots of 16B
      int c = i * 256 + t, r = c >> 3, q = c & 7, p = q ^ (r & 7);
      async16(ldsA + (i * 256 + wave * 64) * 16,
              (const char*)A + (size_t)(m0 + r) * 1024 + kt * 128 + p * 16);
    }
#pragma unroll
    for (int i = 0; i < 4; ++i) {          // B: 1024 slots of 16B
      int c = i * 256 + t, r = c >> 3, q = c & 7, p = q ^ (r & 7);
      async16(ldsB + (i * 256 + wave * 64) * 16,
              (const char*)Bt + (size_t)(n0 + r) * 1024 + kt * 128 + p * 16);
    }
    __syncthreads();  // drains vmcnt per barrier semantics
#pragma unroll
    for (int ks = 0; ks < 2; ++ks) {
      bf16x8 af[4], bfm[4];
#pragma unroll
      for (int i = 0; i < 4; ++i) {
        int r = wr * 64 + i * 16 + llo;    // A-frag: row=lane&15(+tile), k=quad*8+j
        af[i] = *(const bf16x8*)(ldsA + r * 128 + (((ks * 4 + lhi) ^ (r & 7)) << 4));
      }
#pragma unroll
      for (int j = 0; j < 4; ++j) {
        int r = wc * 64 + j * 16 + llo;    // B-frag: col=lane&15(+tile)
        bfm[j] = *(const bf16x8*)(ldsB + r * 128 + (((ks * 4 + lhi) ^ (r & 7)) << 4));
      }
#pragma unroll
      for (int i = 0; i < 4; ++i)
#pragma unroll
        for (int j = 0; j < 4; ++j)
          acc[i][j] = MFMA16(af[i], bfm[j], acc[i][j], 0, 0, 0);
    }
  }
}

// ---------------- K2: GEMM1 + gate-scale epilogue -> T (bf16) --------------
__global__ __launch_bounds__(256, 3) void gemm1_kernel(
    const bf16_t* __restrict__ xbf, const bf16_t* __restrict__ VCc,
    const float* __restrict__ g, bf16_t* __restrict__ T) {
  int t = threadIdx.x;
  int m0 = blockIdx.x * 128, n0 = blockIdx.y * 128;
  floatx4 acc[4][4];
#pragma unroll
  for (int i = 0; i < 4; ++i)
#pragma unroll
    for (int j = 0; j < 4; ++j) acc[i][j] = (floatx4){0.f, 0.f, 0.f, 0.f};
  gemm_core128(xbf, VCc, m0, n0, t, acc);
  const int wave = t >> 6, lane = t & 63;
  const int wr = wave >> 1, wc = wave & 1;
  const int lhi = lane >> 4, llo = lane & 15;
  const int e = (n0 >> 6) + wc;  // 64-col block = one expert (wave-uniform)
#pragma unroll
  for (int i = 0; i < 4; ++i) {
#pragma unroll
    for (int r = 0; r < 4; ++r) {
      int m = m0 + wr * 64 + i * 16 + lhi * 4 + r;  // C/D: col=lane&15, row=quad*4+reg
      float gv = g[(size_t)m * 8 + e];
#pragma unroll
      for (int j = 0; j < 4; ++j) {
        int n = n0 + wc * 64 + j * 16 + llo;
        T[(size_t)m * 512 + n] = (bf16_t)(acc[i][j][r] * gv);
      }
    }
  }
}

// ---------------- K3: GEMM2 + final epilogue -> out (f32) ------------------
__global__ __launch_bounds__(256, 3) void gemm2_kernel(
    const bf16_t* __restrict__ T, const bf16_t* __restrict__ Ut,
    const float* __restrict__ g, const float* __restrict__ bvec,
    const float* __restrict__ x0, const float* __restrict__ x,
    float* __restrict__ out) {
  int t = threadIdx.x;
  int m0 = blockIdx.x * 128, n0 = blockIdx.y * 128;
  floatx4 acc[4][4];
#pragma unroll
  for (int i = 0; i < 4; ++i)
#pragma unroll
    for (int j = 0; j < 4; ++j) acc[i][j] = (floatx4){0.f, 0.f, 0.f, 0.f};
  gemm_core128(T, Ut, m0, n0, t, acc);
  const int wave = t >> 6, lane = t & 63;
  const int wr = wave >> 1, wc = wave & 1;
  const int lhi = lane >> 4, llo = lane & 15;
  float bb[4][8];  // bvec[e][n_j] for this lane's 4 column positions
#pragma unroll
  for (int j = 0; j < 4; ++j) {
    int n = n0 + wc * 64 + j * 16 + llo;
#pragma unroll
    for (int e = 0; e < 8; ++e) bb[j][e] = bvec[(size_t)e * 512 + n];
  }
#pragma unroll
  for (int i = 0; i < 4; ++i) {
#pragma unroll
    for (int r = 0; r < 4; ++r) {
      int m = m0 + wr * 64 + i * 16 + lhi * 4 + r;
      float g8[8], gsum = 0.f;
#pragma unroll
      for (int e = 0; e < 8; ++e) { g8[e] = g[(size_t)m * 8 + e]; gsum += g8[e]; }
#pragma unroll
      for (int j = 0; j < 4; ++j) {
        int n = n0 + wc * 64 + j * 16 + llo;
        float bias = 0.f;
#pragma unroll
        for (int e = 0; e < 8; ++e) bias += g8[e] * bb[j][e];
        size_t idx = (size_t)m * 512 + n;
        out[idx] = x0[idx] * acc[i][j][r] + bias + x[idx] * gsum;
      }
    }
  }
}

// ---------------- launch ----------------------------------------------------
extern "C" void kernel_launch(void* const* d_in, const int* in_sizes, int n_in,
                              void* d_out, int out_size, void* d_ws, size_t ws_size,
                              hipStream_t stream) {
  const float* x0 = (const float*)d_in[0];
  const float* x  = (const float*)d_in[1];
  const float* U  = (const float*)d_in[2];
  const float* V  = (const float*)d_in[3];
  const float* C  = (const float*)d_in[4];
  const float* bv = (const float*)d_in[5];
  const float* Wg = (const float*)d_in[6];
  const float* bg = (const float*)d_in[7];
  float* out = (float*)d_out;

  char* ws = (char*)d_ws;
  bf16_t* xbf = (bf16_t*)(ws);                               // 16,777,216 B
  bf16_t* T   = (bf16_t*)(ws + 16777216);                    // 16,777,216 B
  bf16_t* VCc = (bf16_t*)(ws + 33554432);                    //    524,288 B
  bf16_t* Ut  = (bf16_t*)(ws + 34078720);                    //    524,288 B
  float*  g   = (float*)(ws + 34603008);                     //    524,288 B

  prep_kernel<<<128, 256, 0, stream>>>(U, V, C, VCc, Ut);
  gate_kernel<<<4096, 256, 0, stream>>>(x, Wg, bg, xbf, g);
  gemm1_kernel<<<dim3(128, 4), 256, 0, stream>>>(xbf, VCc, g, T);
  gemm2_kernel<<<dim3(128, 4), 256, 0, stream>>>(T, Ut, g, bv, x0, x, out);
}

// Round 7
// 158.971 us; speedup vs baseline: 1.1490x; 1.0412x over previous
//
#include <hip/hip_runtime.h>
#include <math.h>

// Problem: B=16384, D=512, R=64, E=8.
// out = x0 * (sum_e g_e * (x @ V[e]^T C[e] U[e]^T)) + g@b + x*sum(g)
// Folded: VCc[n=e*64+s][d] = sum_r V[e,r,d] C[e,r,s]  (Bt for GEMM1, K=d contig)
//         Ut [d][n=e*64+s] = U[e,d,s]                  (Bt for GEMM2, K=n contig)
//
// R9: R8 core kept verbatim (128x128 tile, drain-style, 3 blk/CU: the verified
// optimum at this tile size — m228d shows 2ph-dbuf is WORSE at 128²).
// Deltas: (1) prep+gate merged into one setup launch (prep blocks first);
// (2) g-tile (4KB) staged to LDS in both GEMMs; epilogue gate reads become
// LDS broadcasts instead of 16-128 scattered global scalar loads per thread.
// Top-5 dispatches are harness 256MiB workspace fills (~41us @82% HBM) — fixed
// overhead outside kernel control; optimization target is the kernel sum.

typedef __bf16 bf16_t;
typedef __attribute__((ext_vector_type(8))) __bf16 bf16x8;
typedef __attribute__((ext_vector_type(4))) __bf16 bf16x4;
typedef __attribute__((ext_vector_type(4))) float  floatx4;

#define MFMA16 __builtin_amdgcn_mfma_f32_16x16x32_bf16

// async 16B/lane global->LDS (LDS dest = wave-uniform base + lane*16)
__device__ __forceinline__ void async16(void* lds, const void* gp) {
  __builtin_amdgcn_global_load_lds(
      (__attribute__((address_space(1))) void*)(gp),
      (__attribute__((address_space(3))) void*)(lds), 16, 0, 0);
}

// ---------------- K0: setup = weight prep (blocks 0..127) + gate (128..4223) --
__global__ __launch_bounds__(256) void setup_kernel(
    const float* __restrict__ U, const float* __restrict__ V, const float* __restrict__ C,
    const float* __restrict__ x, const float* __restrict__ Wg, const float* __restrict__ bg,
    bf16_t* __restrict__ VCc, bf16_t* __restrict__ Ut,
    bf16_t* __restrict__ xbf, float* __restrict__ g) {
  __shared__ alignas(16) char ldsbuf[32768];
  const int t = threadIdx.x;
  if (blockIdx.x < 128) {
    const int b = blockIdx.x;
    if (b < 64) {
      float* ldsC = (float*)ldsbuf;            // [64 r][64 s]
      float* ldsV = (float*)(ldsbuf + 16384);  // [64 r][64 d]
      const int e = b >> 3, db = b & 7;
#pragma unroll
      for (int i = 0; i < 4; ++i) {
        int c = i * 256 + t;
        async16(ldsbuf + c * 16, (const char*)C + (size_t)e * 16384 + c * 16);
      }
#pragma unroll
      for (int i = 0; i < 4; ++i) {
        int c = i * 256 + t, r = c >> 4, cc = c & 15;
        async16(ldsbuf + 16384 + c * 16,
                (const char*)V + (size_t)(e * 64 + r) * 2048 + db * 256 + cc * 16);
      }
      __syncthreads();
      const int s = t & 63, dg = t >> 6;
      float acc16[16];
#pragma unroll
      for (int k = 0; k < 16; ++k) acc16[k] = 0.f;
#pragma unroll 4
      for (int r = 0; r < 64; ++r) {
        float cv = ldsC[r * 64 + s];
        floatx4 v[4];
#pragma unroll
        for (int j = 0; j < 4; ++j) v[j] = *(const floatx4*)(ldsV + r * 64 + dg * 16 + j * 4);
#pragma unroll
        for (int j = 0; j < 4; ++j)
#pragma unroll
          for (int k = 0; k < 4; ++k) acc16[j * 4 + k] = fmaf(v[j][k], cv, acc16[j * 4 + k]);
      }
      bf16_t* dst = VCc + (size_t)(e * 64 + s) * 512 + db * 64 + dg * 16;
      bf16x8 o0, o1;
#pragma unroll
      for (int k = 0; k < 8; ++k) { o0[k] = (bf16_t)acc16[k]; o1[k] = (bf16_t)acc16[8 + k]; }
      *(bf16x8*)dst = o0;
      *(bf16x8*)(dst + 8) = o1;
    } else {
      const int base = (b - 64) * 4096 + t * 16;
      const int d = base >> 9, n0 = base & 511;
      const int e = n0 >> 6, s0 = n0 & 63;
      const float* src = U + ((size_t)e * 512 + d) * 64 + s0;
      bf16x8 o0, o1;
#pragma unroll
      for (int k = 0; k < 8; ++k) { o0[k] = (bf16_t)src[k]; o1[k] = (bf16_t)src[8 + k]; }
      *(bf16x8*)(Ut + base) = o0;
      *(bf16x8*)(Ut + base + 8) = o1;
    }
  } else {
    // ---- gate path (verbatim-verified): row = (blk-128)*4 + wave ----
    int wave = t >> 6, lane = t & 63;
    int row = (blockIdx.x - 128) * 4 + wave;
    const float4* xr = (const float4*)(x + (size_t)row * 512);
    float4 v0 = xr[lane];
    float4 v1 = xr[lane + 64];
    bf16x4* xb = (bf16x4*)(xbf + (size_t)row * 512);
    bf16x4 b0, b1;
    b0.x = (bf16_t)v0.x; b0.y = (bf16_t)v0.y; b0.z = (bf16_t)v0.z; b0.w = (bf16_t)v0.w;
    b1.x = (bf16_t)v1.x; b1.y = (bf16_t)v1.y; b1.z = (bf16_t)v1.z; b1.w = (bf16_t)v1.w;
    xb[lane] = b0;
    xb[lane + 64] = b1;
    float acc[8];
#pragma unroll
    for (int e = 0; e < 8; ++e) {
      const float4* wp = (const float4*)(Wg + (size_t)e * 512);
      float4 w0 = wp[lane], w1 = wp[lane + 64];
      acc[e] = v0.x * w0.x + v0.y * w0.y + v0.z * w0.z + v0.w * w0.w +
               v1.x * w1.x + v1.y * w1.y + v1.z * w1.z + v1.w * w1.w;
    }
#pragma unroll
    for (int e = 0; e < 8; ++e) {
#pragma unroll
      for (int off = 32; off > 0; off >>= 1) acc[e] += __shfl_xor(acc[e], off, 64);
    }
    float z[8], mx = -1e30f;
#pragma unroll
    for (int e = 0; e < 8; ++e) { z[e] = acc[e] + bg[e]; mx = fmaxf(mx, z[e]); }
    float s = 0.f;
#pragma unroll
    for (int e = 0; e < 8; ++e) { z[e] = __expf(z[e] - mx); s += z[e]; }
    float inv = 1.f / s;
    if (lane == 0) {
#pragma unroll
      for (int e = 0; e < 8; ++e) g[(size_t)row * 8 + e] = z[e] * inv;
    }
  }
}

// ---------------- shared GEMM core: 128x128 tile, BK=64, 4 waves 64x64 -----
// A [M][512] bf16 row-major; Bt [N][512] bf16 (column n's K contiguous).
// LDS chunk swizzle: 16B slot q of row r holds global slot q^(r&7) within the
// 128B row (inverse-swizzled source, linear global_load_lds dest; read XORs
// back). Single-buffered, 2 barriers/K-step; co-resident blocks absorb drains.
__device__ __forceinline__ void gemm_core128(
    char* lds, const bf16_t* __restrict__ A, const bf16_t* __restrict__ Bt,
    int m0, int n0, int t, floatx4 acc[4][4]) {
  char* ldsA = lds;           // [128 rows][128B]
  char* ldsB = lds + 16384;   // [128 rows][128B]
  const int wave = t >> 6, lane = t & 63;
  const int wr = wave >> 1, wc = wave & 1;
  const int lhi = lane >> 4, llo = lane & 15;
#pragma unroll 1
  for (int kt = 0; kt < 8; ++kt) {
    __syncthreads();  // protect LDS from previous iter's readers
#pragma unroll
    for (int i = 0; i < 4; ++i) {          // A: 1024 slots of 16B
      int c = i * 256 + t, r = c >> 3, q = c & 7, p = q ^ (r & 7);
      async16(ldsA + (i * 256 + wave * 64) * 16,
              (const char*)A + (size_t)(m0 + r) * 1024 + kt * 128 + p * 16);
    }
#pragma unroll
    for (int i = 0; i < 4; ++i) {          // B: 1024 slots of 16B
      int c = i * 256 + t, r = c >> 3, q = c & 7, p = q ^ (r & 7);
      async16(ldsB + (i * 256 + wave * 64) * 16,
              (const char*)Bt + (size_t)(n0 + r) * 1024 + kt * 128 + p * 16);
    }
    __syncthreads();  // drains vmcnt per barrier semantics
#pragma unroll
    for (int ks = 0; ks < 2; ++ks) {
      bf16x8 af[4], bfm[4];
#pragma unroll
      for (int i = 0; i < 4; ++i) {
        int r = wr * 64 + i * 16 + llo;    // A-frag: row=lane&15(+tile), k=quad*8+j
        af[i] = *(const bf16x8*)(ldsA + r * 128 + (((ks * 4 + lhi) ^ (r & 7)) << 4));
      }
#pragma unroll
      for (int j = 0; j < 4; ++j) {
        int r = wc * 64 + j * 16 + llo;    // B-frag: col=lane&15(+tile)
        bfm[j] = *(const bf16x8*)(ldsB + r * 128 + (((ks * 4 + lhi) ^ (r & 7)) << 4));
      }
#pragma unroll
      for (int i = 0; i < 4; ++i)
#pragma unroll
        for (int j = 0; j < 4; ++j)
          acc[i][j] = MFMA16(af[i], bfm[j], acc[i][j], 0, 0, 0);
    }
  }
}

// ---------------- K2: GEMM1 + gate-scale epilogue -> T (bf16) --------------
__global__ __launch_bounds__(256, 3) void gemm1_kernel(
    const bf16_t* __restrict__ xbf, const bf16_t* __restrict__ VCc,
    const float* __restrict__ g, bf16_t* __restrict__ T) {
  __shared__ alignas(16) char lds[36864];
  float* ldsGf = (float*)(lds + 32768);    // [128 rows][8] gates
  int t = threadIdx.x;
  int m0 = blockIdx.x * 128, n0 = blockIdx.y * 128;
  // stage g-tile (4KB) — drained by core's first __syncthreads
  async16(ldsGf + (t >> 6) * 256, (const char*)g + (size_t)m0 * 32 + t * 16);
  floatx4 acc[4][4];
#pragma unroll
  for (int i = 0; i < 4; ++i)
#pragma unroll
    for (int j = 0; j < 4; ++j) acc[i][j] = (floatx4){0.f, 0.f, 0.f, 0.f};
  gemm_core128(lds, xbf, VCc, m0, n0, t, acc);
  const int wave = t >> 6, lane = t & 63;
  const int wr = wave >> 1, wc = wave & 1;
  const int lhi = lane >> 4, llo = lane & 15;
  const int e = (n0 >> 6) + wc;  // 64-col block = one expert (wave-uniform)
#pragma unroll
  for (int i = 0; i < 4; ++i) {
#pragma unroll
    for (int r = 0; r < 4; ++r) {
      int lrow = wr * 64 + i * 16 + lhi * 4 + r;    // C/D: col=lane&15, row=quad*4+reg
      float gv = ldsGf[lrow * 8 + e];
#pragma unroll
      for (int j = 0; j < 4; ++j) {
        int n = n0 + wc * 64 + j * 16 + llo;
        T[(size_t)(m0 + lrow) * 512 + n] = (bf16_t)(acc[i][j][r] * gv);
      }
    }
  }
}

// ---------------- K3: GEMM2 + final epilogue -> out (f32) ------------------
__global__ __launch_bounds__(256, 3) void gemm2_kernel(
    const bf16_t* __restrict__ T, const bf16_t* __restrict__ Ut,
    const float* __restrict__ g, const float* __restrict__ bvec,
    const float* __restrict__ x0, const float* __restrict__ x,
    float* __restrict__ out) {
  __shared__ alignas(16) char lds[36864];
  float* ldsGf = (float*)(lds + 32768);    // [128 rows][8] gates
  int t = threadIdx.x;
  int m0 = blockIdx.x * 128, n0 = blockIdx.y * 128;
  async16(ldsGf + (t >> 6) * 256, (const char*)g + (size_t)m0 * 32 + t * 16);
  floatx4 acc[4][4];
#pragma unroll
  for (int i = 0; i < 4; ++i)
#pragma unroll
    for (int j = 0; j < 4; ++j) acc[i][j] = (floatx4){0.f, 0.f, 0.f, 0.f};
  gemm_core128(lds, T, Ut, m0, n0, t, acc);
  const int wave = t >> 6, lane = t & 63;
  const int wr = wave >> 1, wc = wave & 1;
  const int lhi = lane >> 4, llo = lane & 15;
  float bb[4][8];  // bvec[e][n_j] for this lane's 4 column positions
#pragma unroll
  for (int j = 0; j < 4; ++j) {
    int n = n0 + wc * 64 + j * 16 + llo;
#pragma unroll
    for (int e = 0; e < 8; ++e) bb[j][e] = bvec[(size_t)e * 512 + n];
  }
#pragma unroll
  for (int i = 0; i < 4; ++i) {
#pragma unroll
    for (int r = 0; r < 4; ++r) {
      int lrow = wr * 64 + i * 16 + lhi * 4 + r;
      floatx4 ga = *(const floatx4*)(ldsGf + lrow * 8);
      floatx4 gb = *(const floatx4*)(ldsGf + lrow * 8 + 4);
      float g8[8] = {ga[0], ga[1], ga[2], ga[3], gb[0], gb[1], gb[2], gb[3]};
      float gsum = ga[0] + ga[1] + ga[2] + ga[3] + gb[0] + gb[1] + gb[2] + gb[3];
#pragma unroll
      for (int j = 0; j < 4; ++j) {
        int n = n0 + wc * 64 + j * 16 + llo;
        float bias = 0.f;
#pragma unroll
        for (int e = 0; e < 8; ++e) bias += g8[e] * bb[j][e];
        size_t idx = (size_t)(m0 + lrow) * 512 + n;
        out[idx] = x0[idx] * acc[i][j][r] + bias + x[idx] * gsum;
      }
    }
  }
}

// ---------------- launch ----------------------------------------------------
extern "C" void kernel_launch(void* const* d_in, const int* in_sizes, int n_in,
                              void* d_out, int out_size, void* d_ws, size_t ws_size,
                              hipStream_t stream) {
  const float* x0 = (const float*)d_in[0];
  const float* x  = (const float*)d_in[1];
  const float* U  = (const float*)d_in[2];
  const float* V  = (const float*)d_in[3];
  const float* C  = (const float*)d_in[4];
  const float* bv = (const float*)d_in[5];
  const float* Wg = (const float*)d_in[6];
  const float* bg = (const float*)d_in[7];
  float* out = (float*)d_out;

  char* ws = (char*)d_ws;
  bf16_t* xbf = (bf16_t*)(ws);                               // 16,777,216 B
  bf16_t* T   = (bf16_t*)(ws + 16777216);                    // 16,777,216 B
  bf16_t* VCc = (bf16_t*)(ws + 33554432);                    //    524,288 B
  bf16_t* Ut  = (bf16_t*)(ws + 34078720);                    //    524,288 B
  float*  g   = (float*)(ws + 34603008);                     //    524,288 B

  setup_kernel<<<4224, 256, 0, stream>>>(U, V, C, x, Wg, bg, VCc, Ut, xbf, g);
  gemm1_kernel<<<dim3(128, 4), 256, 0, stream>>>(xbf, VCc, g, T);
  gemm2_kernel<<<dim3(128, 4), 256, 0, stream>>>(T, Ut, g, bv, x0, x, out);
}